// Round 4
// baseline (611.820 us; speedup 1.0000x reference)
//
#include <hip/hip_runtime.h>

#define H 128

typedef __attribute__((ext_vector_type(8))) short bf16x8;
typedef __attribute__((ext_vector_type(4))) float f32x4;
typedef unsigned int uint;
typedef unsigned short ushort;

__device__ __forceinline__ ushort f2bf(float f) {
    uint u = __builtin_bit_cast(uint, f);
    uint r = u + 0x7FFFu + ((u >> 16) & 1u);
    return (ushort)(r >> 16);
}
__device__ __forceinline__ float bf_lo(uint u) {
    return __builtin_bit_cast(float, u << 16);
}
__device__ __forceinline__ float bf_hi(uint u) {
    return __builtin_bit_cast(float, u & 0xFFFF0000u);
}

// =======================================================================
// CSR build, bucket-local to avoid random-4B-write line ping-pong.
// bucket = row >> 10 (1024 rows). Requires NB <= 1024 (N <= ~1M).
// =======================================================================

__global__ void bucket_hist(const int* __restrict__ ei, int E, int NB, int NBLK,
                            int* __restrict__ cntg) {
    __shared__ int cnt[1024];
    int blk = blockIdx.x, t = threadIdx.x;
    for (int b = t; b < NB; b += 256) cnt[b] = 0;
    __syncthreads();
    int lo = blk << 13, hi = min(lo + 8192, E);
    for (int e = lo + t; e < hi; e += 256) atomicAdd(&cnt[ei[e] >> 10], 1);
    __syncthreads();
    for (int b = t; b < NB; b += 256) cntg[b * NBLK + blk] = cnt[b];
}

// ---- two-level flat scan (src[M] -> dst[M] exclusive, dst[M]=total) ----

__global__ void scan_reduce(const int* __restrict__ src, int* __restrict__ bsum, int M) {
    __shared__ int sm[256];
    int lo = blockIdx.x * 512;
    int t = threadIdx.x;
    int a = (lo + t < M) ? src[lo + t] : 0;
    int b = (lo + 256 + t < M) ? src[lo + 256 + t] : 0;
    sm[t] = a + b;
    __syncthreads();
    for (int d = 128; d; d >>= 1) {
        if (t < d) sm[t] += sm[t + d];
        __syncthreads();
    }
    if (t == 0) bsum[blockIdx.x] = sm[0];
}

__global__ void scan_bsums(int* __restrict__ bsum, int* __restrict__ dst, int B, int M) {
    __shared__ int s[1024];
    int t = threadIdx.x;
    int v = (t < B) ? bsum[t] : 0;
    s[t] = v;
    __syncthreads();
    for (int d = 1; d < 1024; d <<= 1) {
        int u = (t >= d) ? s[t - d] : 0;
        __syncthreads();
        s[t] += u;
        __syncthreads();
    }
    if (t < B) bsum[t] = s[t] - v;
    if (t == 1023) dst[M] = s[1023];
}

__global__ void scan_write(const int* __restrict__ src, const int* __restrict__ bsum,
                           int* __restrict__ dst, int M) {
    __shared__ int sm[256];
    int lo = blockIdx.x * 512;
    int t = threadIdx.x;
    int i0 = lo + 2 * t, i1 = i0 + 1;
    int d0 = (i0 < M) ? src[i0] : 0;
    int d1 = (i1 < M) ? src[i1] : 0;
    int p = d0 + d1;
    sm[t] = p;
    __syncthreads();
    for (int d = 1; d < 256; d <<= 1) {
        int u = (t >= d) ? sm[t - d] : 0;
        __syncthreads();
        sm[t] += u;
        __syncthreads();
    }
    int ex = sm[t] - p + bsum[blockIdx.x];
    if (i0 < M) dst[i0] = ex;
    if (i1 < M) dst[i1] = ex + d0;
}

__global__ void bucket_scatter(const int* __restrict__ ei, int E, int NB, int NBLK,
                               const int* __restrict__ ebase, int2* __restrict__ ebuf) {
    __shared__ int lcnt[1024];
    __shared__ int lbase[1024];
    int blk = blockIdx.x, t = threadIdx.x;
    for (int b = t; b < NB; b += 256) {
        lcnt[b] = 0;
        lbase[b] = ebase[b * NBLK + blk];
    }
    __syncthreads();
    int lo = blk << 13, hi = min(lo + 8192, E);
    for (int e = lo + t; e < hi; e += 256) {
        int r = ei[e], c = ei[E + e];
        int b = r >> 10;
        int pos = lbase[b] + atomicAdd(&lcnt[b], 1);
        ebuf[pos] = make_int2(r, c);
    }
}

// one block per bucket: LDS histogram + scan -> deg/off/cols (all writes local & dense)
__global__ void bucket_csr(const int2* __restrict__ ebuf, const int* __restrict__ ebase,
                           int NB, int NBLK, int E, int N,
                           int* __restrict__ deg, int* __restrict__ off,
                           int* __restrict__ colss) {
    __shared__ int rcnt[1024], rloff[1024], tsum[256];
    int b = blockIdx.x, t = threadIdx.x;
    int rowbase = b << 10;
    int rs = ebase[b * NBLK];
    int re = (b == NB - 1) ? E : ebase[(b + 1) * NBLK];
    for (int i = t; i < 1024; i += 256) rcnt[i] = 0;
    __syncthreads();
    for (int e = rs + t; e < re; e += 256) atomicAdd(&rcnt[ebuf[e].x - rowbase], 1);
    __syncthreads();
    int s = 0, part[4];
#pragma unroll
    for (int k = 0; k < 4; ++k) { part[k] = s; s += rcnt[t * 4 + k]; }
    tsum[t] = s;
    __syncthreads();
    int self = s;
    for (int d = 1; d < 256; d <<= 1) {
        int v = (t >= d) ? tsum[t - d] : 0;
        __syncthreads();
        tsum[t] += v;
        __syncthreads();
    }
    int pre = tsum[t] - self;
#pragma unroll
    for (int k = 0; k < 4; ++k) {
        int lr = t * 4 + k, row = rowbase + lr;
        rloff[lr] = pre + part[k];
        if (row < N) {
            deg[row] = rcnt[lr];
            off[row] = rs + rloff[lr];
        }
    }
    if (b == NB - 1 && t == 0) off[N] = E;
    __syncthreads();
    for (int i = t; i < 1024; i += 256) rcnt[i] = 0;
    __syncthreads();
    for (int e = rs + t; e < re; e += 256) {
        int2 rc = ebuf[e];
        int lr = rc.x - rowbase;
        int pz = atomicAdd(&rcnt[lr], 1);
        colss[rs + rloff[lr] + pz] = rc.y;
    }
}

// c_i[k] = sum_j W3[i][k][j] * relu(W4[i][j])
__global__ void cvec_kernel(const float* __restrict__ W3, const float* __restrict__ W4,
                            float* __restrict__ cvec) {
    int i = blockIdx.x, k = threadIdx.x;
    const float* w3 = W3 + i * H * H + k * H;
    const float* w4 = W4 + i * H;
    float s = 0.f;
    for (int j = 0; j < H; ++j) s += w3[j] * fmaxf(w4[j], 0.f);
    cvec[i * H + k] = s;
}

__global__ void cast_bf16(const float* __restrict__ in, ushort* __restrict__ outp, int n8) {
    int i = blockIdx.x * blockDim.x + threadIdx.x;
    if (i >= n8) return;
    const float4* in4 = (const float4*)in;
    float4 a = in4[2 * i], b = in4[2 * i + 1];
    uint4 o;
    o.x = (uint)f2bf(a.x) | ((uint)f2bf(a.y) << 16);
    o.y = (uint)f2bf(a.z) | ((uint)f2bf(a.w) << 16);
    o.z = (uint)f2bf(b.x) | ((uint)f2bf(b.y) << 16);
    o.w = (uint)f2bf(b.z) | ((uint)f2bf(b.w) << 16);
    ((uint4*)outp)[i] = o;
}

// =======================================================================
// Staged-LDS MFMA GEMM (hop0 and the p = h@W2^T GEMMs)
// =======================================================================

template<int ADD_DEGC, int RELU, int OUT_BF16>
__global__ __launch_bounds__(256)
void gemm_mfma(const ushort* __restrict__ A, const ushort* __restrict__ W,
               const int* __restrict__ deg, const float* __restrict__ cvec,
               void* __restrict__ Cout, int N)
{
    __shared__ uint4 A4[128 * 8];
    __shared__ uint4 W4[128 * 8];
    int t = threadIdx.x;
    int w = t >> 6, l = t & 63;
    int lg = l >> 4, lr = l & 15;
    int rowBase = blockIdx.x * 128;

    f32x4 acc[2][8];
#pragma unroll
    for (int rt = 0; rt < 2; ++rt)
#pragma unroll
        for (int ct = 0; ct < 8; ++ct) acc[rt][ct] = (f32x4){0.f, 0.f, 0.f, 0.f};

    const uint4* Ag = (const uint4*)A;
    const uint4* Wg = (const uint4*)W;

    for (int kc = 0; kc < 2; ++kc) {
        if (kc) __syncthreads();
#pragma unroll
        for (int it = 0; it < 4; ++it) {
            int idx = it * 256 + t;
            int r = idx >> 3, s = idx & 7;
            int gr = rowBase + r;
            uint4 v = make_uint4(0, 0, 0, 0);
            if (gr < N) v = Ag[(size_t)gr * 16 + kc * 8 + s];
            A4[r * 8 + (s ^ (r & 7))] = v;
            W4[r * 8 + (s ^ (r & 7))] = Wg[r * 16 + kc * 8 + s];
        }
        __syncthreads();
#pragma unroll
        for (int kk = 0; kk < 2; ++kk) {
            int slot = kk * 4 + lg;
            bf16x8 af[2], bfr[8];
#pragma unroll
            for (int rt = 0; rt < 2; ++rt) {
                int r = w * 32 + rt * 16 + lr;
                af[rt] = *(const bf16x8*)&A4[r * 8 + (slot ^ (r & 7))];
            }
#pragma unroll
            for (int ct = 0; ct < 8; ++ct) {
                int r = ct * 16 + lr;
                bfr[ct] = *(const bf16x8*)&W4[r * 8 + (slot ^ (r & 7))];
            }
#pragma unroll
            for (int rt = 0; rt < 2; ++rt)
#pragma unroll
                for (int ct = 0; ct < 8; ++ct)
                    acc[rt][ct] = __builtin_amdgcn_mfma_f32_16x16x32_bf16(
                        af[rt], bfr[ct], acc[rt][ct], 0, 0, 0);
        }
    }

    float cv[8];
    if (ADD_DEGC) {
#pragma unroll
        for (int ct = 0; ct < 8; ++ct) cv[ct] = cvec[ct * 16 + lr];
    }
#pragma unroll
    for (int rt = 0; rt < 2; ++rt) {
#pragma unroll
        for (int j = 0; j < 4; ++j) {
            int gr = rowBase + w * 32 + rt * 16 + lg * 4 + j;
            if (gr < N) {
                float d = ADD_DEGC ? (float)deg[gr] : 0.f;
#pragma unroll
                for (int ct = 0; ct < 8; ++ct) {
                    int gc = ct * 16 + lr;
                    float v = acc[rt][ct][j];
                    if (ADD_DEGC) v += d * cv[ct];
                    if (RELU) v = fmaxf(v, 0.f);
                    if (OUT_BF16) ((ushort*)Cout)[(size_t)gr * H + gc] = f2bf(v);
                    else ((float*)Cout)[(size_t)gr * H + gc] = v;
                }
            }
        }
    }
}

// =======================================================================
// Fused: bias = x@W1_i^T + deg*c_i (MFMA, frags direct from global, bias
// tile -> 32KB LDS bf16), then dst = relu(bias + sum_nbr p[col]).
// =======================================================================

template<int OUT_BF16>
__global__ __launch_bounds__(256)
void fused_bias_agg(const ushort* __restrict__ xb, const ushort* __restrict__ Wb,
                    const int* __restrict__ deg, const float* __restrict__ cvec,
                    const ushort* __restrict__ p, const int* __restrict__ off,
                    const int* __restrict__ cols, void* __restrict__ dst, int N)
{
    __shared__ ushort biasS[128 * 128];   // 32KB
    int t = threadIdx.x;
    int w = t >> 6, l = t & 63;
    int lg = l >> 4, lr = l & 15;
    int rowBase = blockIdx.x * 128;

    f32x4 acc[2][8];
#pragma unroll
    for (int rt = 0; rt < 2; ++rt)
#pragma unroll
        for (int ct = 0; ct < 8; ++ct) acc[rt][ct] = (f32x4){0.f, 0.f, 0.f, 0.f};

    const uint4* Ag = (const uint4*)xb;
    const uint4* Wg = (const uint4*)Wb;

#pragma unroll
    for (int sl4 = 0; sl4 < 4; ++sl4) {
        int sl = sl4 * 4 + lg;                 // k window = sl*8
        bf16x8 af[2];
#pragma unroll
        for (int rt = 0; rt < 2; ++rt) {
            int gr = rowBase + w * 32 + rt * 16 + lr;
            uint4 v = make_uint4(0, 0, 0, 0);
            if (gr < N) v = Ag[(size_t)gr * 16 + sl];
            af[rt] = *(const bf16x8*)&v;
        }
        bf16x8 bfr[8];
#pragma unroll
        for (int ct = 0; ct < 8; ++ct) {
            uint4 v = Wg[(ct * 16 + lr) * 16 + sl];
            bfr[ct] = *(const bf16x8*)&v;
        }
#pragma unroll
        for (int rt = 0; rt < 2; ++rt)
#pragma unroll
            for (int ct = 0; ct < 8; ++ct)
                acc[rt][ct] = __builtin_amdgcn_mfma_f32_16x16x32_bf16(
                    af[rt], bfr[ct], acc[rt][ct], 0, 0, 0);
    }

    float cv[8];
#pragma unroll
    for (int ct = 0; ct < 8; ++ct) cv[ct] = cvec[ct * 16 + lr];
#pragma unroll
    for (int rt = 0; rt < 2; ++rt) {
#pragma unroll
        for (int j = 0; j < 4; ++j) {
            int lrow = w * 32 + rt * 16 + lg * 4 + j;
            int gr = rowBase + lrow;
            float d = (gr < N) ? (float)deg[gr] : 0.f;
#pragma unroll
            for (int ct = 0; ct < 8; ++ct)
                biasS[lrow * 128 + ct * 16 + lr] = f2bf(acc[rt][ct][j] + d * cv[ct]);
        }
    }
    __syncthreads();

    // ---- aggregation: wave w handles local rows w*32 .. w*32+31 ----
    const uint* pu = (const uint*)p;          // [N][64] packed bf16 pairs
    const uint* bS = (const uint*)biasS;
    for (int i = 0; i < 32; ++i) {
        int lnode = w * 32 + i;
        int node = rowBase + lnode;
        if (node >= N) break;
        int s = off[node], e = off[node + 1];
        float ax = 0.f, ay = 0.f;
        int k = s;
        for (; k + 4 <= e; k += 4) {
            int c0 = cols[k], c1 = cols[k + 1], c2 = cols[k + 2], c3 = cols[k + 3];
            uint v0 = pu[(size_t)c0 * 64 + l];
            uint v1 = pu[(size_t)c1 * 64 + l];
            uint v2 = pu[(size_t)c2 * 64 + l];
            uint v3 = pu[(size_t)c3 * 64 + l];
            ax += bf_lo(v0) + bf_lo(v1) + bf_lo(v2) + bf_lo(v3);
            ay += bf_hi(v0) + bf_hi(v1) + bf_hi(v2) + bf_hi(v3);
        }
        for (; k < e; ++k) {
            uint v = pu[(size_t)cols[k] * 64 + l];
            ax += bf_lo(v);
            ay += bf_hi(v);
        }
        uint bb = bS[lnode * 64 + l];
        float ox = fmaxf(bf_lo(bb) + ax, 0.f);
        float oy = fmaxf(bf_hi(bb) + ay, 0.f);
        if (OUT_BF16) {
            ((uint*)dst)[(size_t)node * 64 + l] = (uint)f2bf(ox) | ((uint)f2bf(oy) << 16);
        } else {
            ((float2*)dst)[(size_t)node * 64 + l] = make_float2(ox, oy);
        }
    }
}

// =======================================================================
// launch
// =======================================================================

extern "C" void kernel_launch(void* const* d_in, const int* in_sizes, int n_in,
                              void* d_out, int out_size, void* d_ws, size_t ws_size,
                              hipStream_t stream)
{
    const float* x  = (const float*)d_in[0];
    const int*   ei = (const int*)d_in[1];
    const float* W1 = (const float*)d_in[2];
    const float* W2 = (const float*)d_in[3];
    const float* W3 = (const float*)d_in[4];
    const float* W4 = (const float*)d_in[5];
    int N   = in_sizes[0] / H;
    int E   = in_sizes[1] / 2;
    int HOP = in_sizes[2] / (H * H);

    int NB   = (N + 1023) >> 10;
    int NBLK = (E + 8191) >> 13;
    int M    = NB * NBLK;

    char* ws = (char*)d_ws;
    int*   deg   = (int*)ws;                  // N
    int*   off   = deg + N;                   // N+1
    int*   colss = off + N + 1;               // E
    int*   cntg  = colss + E;                 // M
    int*   ebase = cntg + M;                  // M+1
    int*   bsum  = ebase + M + 1;             // <=1024
    float* cvec  = (float*)(bsum + 1024);     // HOP*H
    size_t fo = (((size_t)((char*)(cvec + HOP * H) - ws)) + 255) & ~(size_t)255;
    int2*  ebuf = (int2*)(ws + fo);           // E int2
    ushort* xb  = (ushort*)(ebuf + E);        // N*H
    ushort* W1b = xb + (size_t)N * H;         // HOP*H*H
    ushort* W2b = W1b + (size_t)HOP * H * H;  // HOP*H*H
    ushort* p   = W2b + (size_t)HOP * H * H;  // N*H
    ushort* h   = p + (size_t)N * H;          // N*H

    // ---- CSR build ----
    bucket_hist<<<NBLK, 256, 0, stream>>>(ei, E, NB, NBLK, cntg);
    int Bq = (M + 511) / 512;
    scan_reduce<<<Bq, 256, 0, stream>>>(cntg, bsum, M);
    scan_bsums<<<1, 1024, 0, stream>>>(bsum, ebase, Bq, M);
    scan_write<<<Bq, 256, 0, stream>>>(cntg, bsum, ebase, M);
    bucket_scatter<<<NBLK, 256, 0, stream>>>(ei, E, NB, NBLK, ebase, ebuf);
    bucket_csr<<<NB, 256, 0, stream>>>(ebuf, ebase, NB, NBLK, E, N, deg, off, colss);

    cvec_kernel<<<HOP, H, 0, stream>>>(W3, W4, cvec);

    // ---- casts ----
    int nx8 = N * H / 8;
    cast_bf16<<<(nx8 + 255) / 256, 256, 0, stream>>>(x, xb, nx8);
    int nw8 = HOP * H * H / 8;
    cast_bf16<<<(nw8 + 255) / 256, 256, 0, stream>>>(W1, W1b, nw8);
    cast_bf16<<<(nw8 + 255) / 256, 256, 0, stream>>>(W2, W2b, nw8);

    int gblocks = (N + 127) / 128;
    float* out = (float*)d_out;

    if (HOP == 1) {
        gemm_mfma<1, 1, 0><<<gblocks, 256, 0, stream>>>(xb, W1b, deg, cvec, out, N);
        return;
    }
    // hop 0: h = relu(xb@W1[0]^T + deg*c0)
    gemm_mfma<1, 1, 1><<<gblocks, 256, 0, stream>>>(xb, W1b, deg, cvec, h, N);

    for (int i = 1; i < HOP; ++i) {
        int last = (i == HOP - 1);
        // p = h @ W2[i]^T
        gemm_mfma<0, 0, 1><<<gblocks, 256, 0, stream>>>(h, W2b + (size_t)i * H * H,
                                                        nullptr, nullptr, p, N);
        // dst = relu(xb@W1[i]^T + deg*c_i + A p)
        if (last)
            fused_bias_agg<0><<<gblocks, 256, 0, stream>>>(xb, W1b + (size_t)i * H * H,
                                                           deg, cvec + i * H, p, off,
                                                           colss, out, N);
        else
            fused_bias_agg<1><<<gblocks, 256, 0, stream>>>(xb, W1b + (size_t)i * H * H,
                                                           deg, cvec + i * H, p, off,
                                                           colss, h, N);
    }
}

// Round 5
// 305.121 us; speedup vs baseline: 2.0052x; 2.0052x over previous
//
#include <hip/hip_runtime.h>

#define H 128

typedef __attribute__((ext_vector_type(8))) short bf16x8;
typedef __attribute__((ext_vector_type(4))) float f32x4;
typedef unsigned int uint;
typedef unsigned short ushort;

__device__ __forceinline__ ushort f2bf(float f) {
    uint u = __builtin_bit_cast(uint, f);
    uint r = u + 0x7FFFu + ((u >> 16) & 1u);
    return (ushort)(r >> 16);
}
__device__ __forceinline__ float bf_lo(uint u) {
    return __builtin_bit_cast(float, u << 16);
}
__device__ __forceinline__ float bf_hi(uint u) {
    return __builtin_bit_cast(float, u & 0xFFFF0000u);
}

// =======================================================================
// CSR build, bucket-local (keeps 4B writes within per-block-contiguous
// regions -> no HBM line ping-pong; replaced 145us of hist+fill).
// =======================================================================

__global__ void bucket_hist(const int* __restrict__ ei, int E, int NB, int NBLK,
                            int* __restrict__ cntg) {
    __shared__ int cnt[1024];
    int blk = blockIdx.x, t = threadIdx.x;
    for (int b = t; b < NB; b += 256) cnt[b] = 0;
    __syncthreads();
    int lo = blk << 13, hi = min(lo + 8192, E);
    for (int e = lo + t; e < hi; e += 256) atomicAdd(&cnt[ei[e] >> 10], 1);
    __syncthreads();
    for (int b = t; b < NB; b += 256) cntg[b * NBLK + blk] = cnt[b];
}

__global__ void scan_reduce(const int* __restrict__ src, int* __restrict__ bsum, int M) {
    __shared__ int sm[256];
    int lo = blockIdx.x * 512;
    int t = threadIdx.x;
    int a = (lo + t < M) ? src[lo + t] : 0;
    int b = (lo + 256 + t < M) ? src[lo + 256 + t] : 0;
    sm[t] = a + b;
    __syncthreads();
    for (int d = 128; d; d >>= 1) {
        if (t < d) sm[t] += sm[t + d];
        __syncthreads();
    }
    if (t == 0) bsum[blockIdx.x] = sm[0];
}

__global__ void scan_bsums(int* __restrict__ bsum, int* __restrict__ dst, int B, int M) {
    __shared__ int s[1024];
    int t = threadIdx.x;
    int v = (t < B) ? bsum[t] : 0;
    s[t] = v;
    __syncthreads();
    for (int d = 1; d < 1024; d <<= 1) {
        int u = (t >= d) ? s[t - d] : 0;
        __syncthreads();
        s[t] += u;
        __syncthreads();
    }
    if (t < B) bsum[t] = s[t] - v;
    if (t == 1023) dst[M] = s[1023];
}

__global__ void scan_write(const int* __restrict__ src, const int* __restrict__ bsum,
                           int* __restrict__ dst, int M) {
    __shared__ int sm[256];
    int lo = blockIdx.x * 512;
    int t = threadIdx.x;
    int i0 = lo + 2 * t, i1 = i0 + 1;
    int d0 = (i0 < M) ? src[i0] : 0;
    int d1 = (i1 < M) ? src[i1] : 0;
    int p = d0 + d1;
    sm[t] = p;
    __syncthreads();
    for (int d = 1; d < 256; d <<= 1) {
        int u = (t >= d) ? sm[t - d] : 0;
        __syncthreads();
        sm[t] += u;
        __syncthreads();
    }
    int ex = sm[t] - p + bsum[blockIdx.x];
    if (i0 < M) dst[i0] = ex;
    if (i1 < M) dst[i1] = ex + d0;
}

__global__ void bucket_scatter(const int* __restrict__ ei, int E, int NB, int NBLK,
                               const int* __restrict__ ebase, int2* __restrict__ ebuf) {
    __shared__ int lcnt[1024];
    __shared__ int lbase[1024];
    int blk = blockIdx.x, t = threadIdx.x;
    for (int b = t; b < NB; b += 256) {
        lcnt[b] = 0;
        lbase[b] = ebase[b * NBLK + blk];
    }
    __syncthreads();
    int lo = blk << 13, hi = min(lo + 8192, E);
    for (int e = lo + t; e < hi; e += 256) {
        int r = ei[e], c = ei[E + e];
        int b = r >> 10;
        int pos = lbase[b] + atomicAdd(&lcnt[b], 1);
        ebuf[pos] = make_int2(r, c);
    }
}

__global__ void bucket_csr(const int2* __restrict__ ebuf, const int* __restrict__ ebase,
                           int NB, int NBLK, int E, int N,
                           int* __restrict__ deg, int* __restrict__ off,
                           int* __restrict__ colss) {
    __shared__ int rcnt[1024], rloff[1024], tsum[256];
    int b = blockIdx.x, t = threadIdx.x;
    int rowbase = b << 10;
    int rs = ebase[b * NBLK];
    int re = (b == NB - 1) ? E : ebase[(b + 1) * NBLK];
    for (int i = t; i < 1024; i += 256) rcnt[i] = 0;
    __syncthreads();
    for (int e = rs + t; e < re; e += 256) atomicAdd(&rcnt[ebuf[e].x - rowbase], 1);
    __syncthreads();
    int s = 0, part[4];
#pragma unroll
    for (int k = 0; k < 4; ++k) { part[k] = s; s += rcnt[t * 4 + k]; }
    tsum[t] = s;
    __syncthreads();
    int self = s;
    for (int d = 1; d < 256; d <<= 1) {
        int v = (t >= d) ? tsum[t - d] : 0;
        __syncthreads();
        tsum[t] += v;
        __syncthreads();
    }
    int pre = tsum[t] - self;
#pragma unroll
    for (int k = 0; k < 4; ++k) {
        int lr = t * 4 + k, row = rowbase + lr;
        rloff[lr] = pre + part[k];
        if (row < N) {
            deg[row] = rcnt[lr];
            off[row] = rs + rloff[lr];
        }
    }
    if (b == NB - 1 && t == 0) off[N] = E;
    __syncthreads();
    for (int i = t; i < 1024; i += 256) rcnt[i] = 0;
    __syncthreads();
    for (int e = rs + t; e < re; e += 256) {
        int2 rc = ebuf[e];
        int lr = rc.x - rowbase;
        int pz = atomicAdd(&rcnt[lr], 1);
        colss[rs + rloff[lr] + pz] = rc.y;
    }
}

// c_i[k] = sum_j W3[i][k][j] * relu(W4[i][j])
__global__ void cvec_kernel(const float* __restrict__ W3, const float* __restrict__ W4,
                            float* __restrict__ cvec) {
    int i = blockIdx.x, k = threadIdx.x;
    const float* w3 = W3 + i * H * H + k * H;
    const float* w4 = W4 + i * H;
    float s = 0.f;
    for (int j = 0; j < H; ++j) s += w3[j] * fmaxf(w4[j], 0.f);
    cvec[i * H + k] = s;
}

__global__ void cast_bf16(const float* __restrict__ in, ushort* __restrict__ outp, int n8) {
    int i = blockIdx.x * blockDim.x + threadIdx.x;
    if (i >= n8) return;
    const float4* in4 = (const float4*)in;
    float4 a = in4[2 * i], b = in4[2 * i + 1];
    uint4 o;
    o.x = (uint)f2bf(a.x) | ((uint)f2bf(a.y) << 16);
    o.y = (uint)f2bf(a.z) | ((uint)f2bf(a.w) << 16);
    o.z = (uint)f2bf(b.x) | ((uint)f2bf(b.y) << 16);
    o.w = (uint)f2bf(b.z) | ((uint)f2bf(b.w) << 16);
    ((uint4*)outp)[i] = o;
}

// =======================================================================
// Staged-LDS MFMA GEMM: C[n][j] = sum_k A[n][k]*W[j][k] (+deg*cvec) (+relu)
// =======================================================================

template<int ADD_DEGC, int RELU, int OUT_BF16>
__global__ __launch_bounds__(256)
void gemm_mfma(const ushort* __restrict__ A, const ushort* __restrict__ W,
               const int* __restrict__ deg, const float* __restrict__ cvec,
               void* __restrict__ Cout, int N)
{
    __shared__ uint4 A4[128 * 8];
    __shared__ uint4 W4[128 * 8];
    int t = threadIdx.x;
    int w = t >> 6, l = t & 63;
    int lg = l >> 4, lr = l & 15;
    int rowBase = blockIdx.x * 128;

    f32x4 acc[2][8];
#pragma unroll
    for (int rt = 0; rt < 2; ++rt)
#pragma unroll
        for (int ct = 0; ct < 8; ++ct) acc[rt][ct] = (f32x4){0.f, 0.f, 0.f, 0.f};

    const uint4* Ag = (const uint4*)A;
    const uint4* Wg = (const uint4*)W;

    for (int kc = 0; kc < 2; ++kc) {
        if (kc) __syncthreads();
#pragma unroll
        for (int it = 0; it < 4; ++it) {
            int idx = it * 256 + t;
            int r = idx >> 3, s = idx & 7;
            int gr = rowBase + r;
            uint4 v = make_uint4(0, 0, 0, 0);
            if (gr < N) v = Ag[(size_t)gr * 16 + kc * 8 + s];
            A4[r * 8 + (s ^ (r & 7))] = v;
            W4[r * 8 + (s ^ (r & 7))] = Wg[r * 16 + kc * 8 + s];
        }
        __syncthreads();
#pragma unroll
        for (int kk = 0; kk < 2; ++kk) {
            int slot = kk * 4 + lg;
            bf16x8 af[2], bfr[8];
#pragma unroll
            for (int rt = 0; rt < 2; ++rt) {
                int r = w * 32 + rt * 16 + lr;
                af[rt] = *(const bf16x8*)&A4[r * 8 + (slot ^ (r & 7))];
            }
#pragma unroll
            for (int ct = 0; ct < 8; ++ct) {
                int r = ct * 16 + lr;
                bfr[ct] = *(const bf16x8*)&W4[r * 8 + (slot ^ (r & 7))];
            }
#pragma unroll
            for (int rt = 0; rt < 2; ++rt)
#pragma unroll
                for (int ct = 0; ct < 8; ++ct)
                    acc[rt][ct] = __builtin_amdgcn_mfma_f32_16x16x32_bf16(
                        af[rt], bfr[ct], acc[rt][ct], 0, 0, 0);
        }
    }

    float cv[8];
    if (ADD_DEGC) {
#pragma unroll
        for (int ct = 0; ct < 8; ++ct) cv[ct] = cvec[ct * 16 + lr];
    }
#pragma unroll
    for (int rt = 0; rt < 2; ++rt) {
#pragma unroll
        for (int j = 0; j < 4; ++j) {
            int gr = rowBase + w * 32 + rt * 16 + lg * 4 + j;
            if (gr < N) {
                float d = ADD_DEGC ? (float)deg[gr] : 0.f;
#pragma unroll
                for (int ct = 0; ct < 8; ++ct) {
                    int gc = ct * 16 + lr;
                    float v = acc[rt][ct][j];
                    if (ADD_DEGC) v += d * cv[ct];
                    if (RELU) v = fmaxf(v, 0.f);
                    if (OUT_BF16) ((ushort*)Cout)[(size_t)gr * H + gc] = f2bf(v);
                    else ((float*)Cout)[(size_t)gr * H + gc] = v;
                }
            }
        }
    }
}

// =======================================================================
// aggregation: dst[n] = relu(biasb[n] + sum_{e in row n} p[cols[e]])
// one wave per node (max TLP); p, biasb bf16 packed; 8-deep gather unroll
// =======================================================================

template<int OUT_BF16>
__global__ void aggregate_relu3(const ushort* __restrict__ biasb, const ushort* __restrict__ p,
                                const int* __restrict__ off, const int* __restrict__ cols,
                                void* __restrict__ dst, int N)
{
    int node = blockIdx.x * 4 + (threadIdx.x >> 6);
    if (node >= N) return;
    int l = threadIdx.x & 63;
    int s = off[node], e = off[node + 1];
    const uint* pu = (const uint*)p;     // [N][64]
    float ax = 0.f, ay = 0.f;
    int i = s;
    for (; i + 8 <= e; i += 8) {
        uint v0 = pu[(size_t)cols[i]     * 64 + l];
        uint v1 = pu[(size_t)cols[i + 1] * 64 + l];
        uint v2 = pu[(size_t)cols[i + 2] * 64 + l];
        uint v3 = pu[(size_t)cols[i + 3] * 64 + l];
        uint v4 = pu[(size_t)cols[i + 4] * 64 + l];
        uint v5 = pu[(size_t)cols[i + 5] * 64 + l];
        uint v6 = pu[(size_t)cols[i + 6] * 64 + l];
        uint v7 = pu[(size_t)cols[i + 7] * 64 + l];
        ax += bf_lo(v0) + bf_lo(v1) + bf_lo(v2) + bf_lo(v3)
            + bf_lo(v4) + bf_lo(v5) + bf_lo(v6) + bf_lo(v7);
        ay += bf_hi(v0) + bf_hi(v1) + bf_hi(v2) + bf_hi(v3)
            + bf_hi(v4) + bf_hi(v5) + bf_hi(v6) + bf_hi(v7);
    }
    for (; i + 4 <= e; i += 4) {
        uint v0 = pu[(size_t)cols[i]     * 64 + l];
        uint v1 = pu[(size_t)cols[i + 1] * 64 + l];
        uint v2 = pu[(size_t)cols[i + 2] * 64 + l];
        uint v3 = pu[(size_t)cols[i + 3] * 64 + l];
        ax += bf_lo(v0) + bf_lo(v1) + bf_lo(v2) + bf_lo(v3);
        ay += bf_hi(v0) + bf_hi(v1) + bf_hi(v2) + bf_hi(v3);
    }
    for (; i < e; ++i) {
        uint v = pu[(size_t)cols[i] * 64 + l];
        ax += bf_lo(v);
        ay += bf_hi(v);
    }
    uint bb = ((const uint*)biasb)[(size_t)node * 64 + l];
    float ox = fmaxf(bf_lo(bb) + ax, 0.f);
    float oy = fmaxf(bf_hi(bb) + ay, 0.f);
    if (OUT_BF16) {
        ((uint*)dst)[(size_t)node * 64 + l] = (uint)f2bf(ox) | ((uint)f2bf(oy) << 16);
    } else {
        ((float2*)dst)[(size_t)node * 64 + l] = make_float2(ox, oy);
    }
}

// =======================================================================
// launch
// =======================================================================

extern "C" void kernel_launch(void* const* d_in, const int* in_sizes, int n_in,
                              void* d_out, int out_size, void* d_ws, size_t ws_size,
                              hipStream_t stream)
{
    const float* x  = (const float*)d_in[0];
    const int*   ei = (const int*)d_in[1];
    const float* W1 = (const float*)d_in[2];
    const float* W2 = (const float*)d_in[3];
    const float* W3 = (const float*)d_in[4];
    const float* W4 = (const float*)d_in[5];
    int N   = in_sizes[0] / H;
    int E   = in_sizes[1] / 2;
    int HOP = in_sizes[2] / (H * H);

    int NB   = (N + 1023) >> 10;
    int NBLK = (E + 8191) >> 13;
    int M    = NB * NBLK;

    char* ws = (char*)d_ws;
    int*   deg   = (int*)ws;                  // N
    int*   off   = deg + N;                   // N+1
    int*   colss = off + N + 1;               // E
    int*   cntg  = colss + E;                 // M
    int*   ebase = cntg + M;                  // M+1
    int*   bsum  = ebase + M + 1;             // <=1024
    float* cvec  = (float*)(bsum + 1024);     // HOP*H
    size_t fo = (((size_t)((char*)(cvec + HOP * H) - ws)) + 255) & ~(size_t)255;
    int2*  ebuf  = (int2*)(ws + fo);          // E int2
    ushort* xb   = (ushort*)(ebuf + E);       // N*H
    ushort* W1b  = xb + (size_t)N * H;        // HOP*H*H
    ushort* W2b  = W1b + (size_t)HOP * H * H; // HOP*H*H
    ushort* p    = W2b + (size_t)HOP * H * H; // N*H
    ushort* h    = p + (size_t)N * H;         // N*H
    ushort* bias = h + (size_t)N * H;         // N*H

    // ---- CSR build ----
    bucket_hist<<<NBLK, 256, 0, stream>>>(ei, E, NB, NBLK, cntg);
    int Bq = (M + 511) / 512;
    scan_reduce<<<Bq, 256, 0, stream>>>(cntg, bsum, M);
    scan_bsums<<<1, 1024, 0, stream>>>(bsum, ebase, Bq, M);
    scan_write<<<Bq, 256, 0, stream>>>(cntg, bsum, ebase, M);
    bucket_scatter<<<NBLK, 256, 0, stream>>>(ei, E, NB, NBLK, ebase, ebuf);
    bucket_csr<<<NB, 256, 0, stream>>>(ebuf, ebase, NB, NBLK, E, N, deg, off, colss);

    cvec_kernel<<<HOP, H, 0, stream>>>(W3, W4, cvec);

    // ---- casts ----
    int nx8 = N * H / 8;
    cast_bf16<<<(nx8 + 255) / 256, 256, 0, stream>>>(x, xb, nx8);
    int nw8 = HOP * H * H / 8;
    cast_bf16<<<(nw8 + 255) / 256, 256, 0, stream>>>(W1, W1b, nw8);
    cast_bf16<<<(nw8 + 255) / 256, 256, 0, stream>>>(W2, W2b, nw8);

    int gblocks = (N + 127) / 128;
    float* out = (float*)d_out;

    if (HOP == 1) {
        gemm_mfma<1, 1, 0><<<gblocks, 256, 0, stream>>>(xb, W1b, deg, cvec, out, N);
        return;
    }
    // hop 0: h = relu(xb@W1[0]^T + deg*c0)
    gemm_mfma<1, 1, 1><<<gblocks, 256, 0, stream>>>(xb, W1b, deg, cvec, h, N);

    for (int i = 1; i < HOP; ++i) {
        int last = (i == HOP - 1);
        // p = h @ W2[i]^T (bf16)
        gemm_mfma<0, 0, 1><<<gblocks, 256, 0, stream>>>(h, W2b + (size_t)i * H * H,
                                                        nullptr, nullptr, p, N);
        // bias = xb @ W1[i]^T + deg*c_i (bf16, no relu)
        gemm_mfma<1, 0, 1><<<gblocks, 256, 0, stream>>>(xb, W1b + (size_t)i * H * H,
                                                        deg, cvec + i * H, bias, N);
        // dst = relu(bias + A p)
        if (last)
            aggregate_relu3<0><<<(N + 3) / 4, 256, 0, stream>>>(bias, p, off, colss, out, N);
        else
            aggregate_relu3<1><<<(N + 3) / 4, 256, 0, stream>>>(bias, p, off, colss, h, N);
    }
}

// Round 6
// 270.470 us; speedup vs baseline: 2.2621x; 1.1281x over previous
//
#include <hip/hip_runtime.h>

#define H 128

typedef __attribute__((ext_vector_type(8))) short bf16x8;
typedef __attribute__((ext_vector_type(4))) float f32x4;
typedef unsigned int uint;
typedef unsigned short ushort;

__device__ __forceinline__ ushort f2bf(float f) {
    uint u = __builtin_bit_cast(uint, f);
    uint r = u + 0x7FFFu + ((u >> 16) & 1u);
    return (ushort)(r >> 16);
}
__device__ __forceinline__ float bf_lo(uint u) {
    return __builtin_bit_cast(float, u << 16);
}
__device__ __forceinline__ float bf_hi(uint u) {
    return __builtin_bit_cast(float, u & 0xFFFF0000u);
}

// =======================================================================
// CSR build, bucket-local. bucket = row>>10 (NB buckets), edge chunks of
// 4096 (NBLK blocks) for CU-filling parallelism.
// =======================================================================

__global__ void bucket_hist(const int* __restrict__ ei, int E, int NB, int NBLK,
                            int* __restrict__ cntg) {
    __shared__ int cnt[1024];
    int blk = blockIdx.x, t = threadIdx.x;
    for (int b = t; b < NB; b += 256) cnt[b] = 0;
    __syncthreads();
    int lo = blk << 12, hi = min(lo + 4096, E);
    for (int e = lo + t; e < hi; e += 256) atomicAdd(&cnt[ei[e] >> 10], 1);
    __syncthreads();
    for (int b = t; b < NB; b += 256) cntg[b * NBLK + blk] = cnt[b];
}

__global__ void scan_reduce(const int* __restrict__ src, int* __restrict__ bsum, int M) {
    __shared__ int sm[256];
    int lo = blockIdx.x * 512;
    int t = threadIdx.x;
    int a = (lo + t < M) ? src[lo + t] : 0;
    int b = (lo + 256 + t < M) ? src[lo + 256 + t] : 0;
    sm[t] = a + b;
    __syncthreads();
    for (int d = 128; d; d >>= 1) {
        if (t < d) sm[t] += sm[t + d];
        __syncthreads();
    }
    if (t == 0) bsum[blockIdx.x] = sm[0];
}

__global__ void scan_bsums(int* __restrict__ bsum, int* __restrict__ dst, int B, int M) {
    __shared__ int s[1024];
    int t = threadIdx.x;
    int v = (t < B) ? bsum[t] : 0;
    s[t] = v;
    __syncthreads();
    for (int d = 1; d < 1024; d <<= 1) {
        int u = (t >= d) ? s[t - d] : 0;
        __syncthreads();
        s[t] += u;
        __syncthreads();
    }
    if (t < B) bsum[t] = s[t] - v;
    if (t == 1023) dst[M] = s[1023];
}

__global__ void scan_write(const int* __restrict__ src, const int* __restrict__ bsum,
                           int* __restrict__ dst, int M) {
    __shared__ int sm[256];
    int lo = blockIdx.x * 512;
    int t = threadIdx.x;
    int i0 = lo + 2 * t, i1 = i0 + 1;
    int d0 = (i0 < M) ? src[i0] : 0;
    int d1 = (i1 < M) ? src[i1] : 0;
    int p = d0 + d1;
    sm[t] = p;
    __syncthreads();
    for (int d = 1; d < 256; d <<= 1) {
        int u = (t >= d) ? sm[t - d] : 0;
        __syncthreads();
        sm[t] += u;
        __syncthreads();
    }
    int ex = sm[t] - p + bsum[blockIdx.x];
    if (i0 < M) dst[i0] = ex;
    if (i1 < M) dst[i1] = ex + d0;
}

__global__ void bucket_scatter(const int* __restrict__ ei, int E, int NB, int NBLK,
                               const int* __restrict__ ebase, int2* __restrict__ ebuf) {
    __shared__ int lcnt[1024];
    __shared__ int lbase[1024];
    int blk = blockIdx.x, t = threadIdx.x;
    for (int b = t; b < NB; b += 256) {
        lcnt[b] = 0;
        lbase[b] = ebase[b * NBLK + blk];
    }
    __syncthreads();
    int lo = blk << 12, hi = min(lo + 4096, E);
    for (int e = lo + t; e < hi; e += 256) {
        int r = ei[e], c = ei[E + e];
        int b = r >> 10;
        int pos = lbase[b] + atomicAdd(&lcnt[b], 1);
        ebuf[pos] = make_int2(r, c);
    }
}

// one block (1024 thr) per bucket: LDS histogram + scan -> deg/off/cols
__global__ __launch_bounds__(1024)
void bucket_csr(const int2* __restrict__ ebuf, const int* __restrict__ ebase,
                int NB, int NBLK, int E, int N,
                int* __restrict__ deg, int* __restrict__ off,
                int* __restrict__ colss) {
    __shared__ int rcnt[1024], rloff[1024];
    int b = blockIdx.x, t = threadIdx.x;
    int rowbase = b << 10;
    int rs = ebase[b * NBLK];
    int re = (b == NB - 1) ? E : ebase[(b + 1) * NBLK];
    rcnt[t] = 0;
    __syncthreads();
    for (int e = rs + t; e < re; e += 1024) atomicAdd(&rcnt[ebuf[e].x - rowbase], 1);
    __syncthreads();
    int v = rcnt[t];
    rloff[t] = v;
    __syncthreads();
    for (int d = 1; d < 1024; d <<= 1) {
        int u = (t >= d) ? rloff[t - d] : 0;
        __syncthreads();
        rloff[t] += u;
        __syncthreads();
    }
    int ex = rloff[t] - v;
    int row = rowbase + t;
    if (row < N) {
        deg[row] = v;
        off[row] = rs + ex;
    }
    if (b == NB - 1 && t == 0) off[N] = E;
    __syncthreads();
    rloff[t] = ex;
    rcnt[t] = 0;
    __syncthreads();
    for (int e = rs + t; e < re; e += 1024) {
        int2 rc = ebuf[e];
        int lr = rc.x - rowbase;
        int pz = atomicAdd(&rcnt[lr], 1);
        colss[rs + rloff[lr] + pz] = rc.y;
    }
}

// c_i[k] = sum_j W3[i][k][j] * relu(W4[i][j])
__global__ void cvec_kernel(const float* __restrict__ W3, const float* __restrict__ W4,
                            float* __restrict__ cvec) {
    int i = blockIdx.x, k = threadIdx.x;
    const float* w3 = W3 + i * H * H + k * H;
    const float* w4 = W4 + i * H;
    float s = 0.f;
    for (int j = 0; j < H; ++j) s += w3[j] * fmaxf(w4[j], 0.f);
    cvec[i * H + k] = s;
}

__global__ void cast_bf16(const float* __restrict__ in, ushort* __restrict__ outp, int n8) {
    int i = blockIdx.x * blockDim.x + threadIdx.x;
    if (i >= n8) return;
    const float4* in4 = (const float4*)in;
    float4 a = in4[2 * i], b = in4[2 * i + 1];
    uint4 o;
    o.x = (uint)f2bf(a.x) | ((uint)f2bf(a.y) << 16);
    o.y = (uint)f2bf(a.z) | ((uint)f2bf(a.w) << 16);
    o.z = (uint)f2bf(b.x) | ((uint)f2bf(b.y) << 16);
    o.w = (uint)f2bf(b.z) | ((uint)f2bf(b.w) << 16);
    ((uint4*)outp)[i] = o;
}

// =======================================================================
// multi_xproj: stage x-tile (f32 -> bf16) ONCE, then for each hop j:
//   stage W1b[j] (L2-resident), compute tile @ W1_j^T + deg*c_j.
//   j==0 -> relu -> h (bf16; or out f32 if HOP==1). j>=1 -> bias slab j-1.
// LDS: A 32KB + W 32KB = 64KB.
// =======================================================================

__global__ __launch_bounds__(256)
void multi_xproj(const float* __restrict__ x, const ushort* __restrict__ W1b,
                 const int* __restrict__ deg, const float* __restrict__ cvec,
                 ushort* __restrict__ h, ushort* __restrict__ bias,
                 float* __restrict__ outf, int N, int HOP)
{
    __shared__ uint4 A4[128 * 16];
    __shared__ uint4 W4s[128 * 16];
    int t = threadIdx.x;
    int wv = t >> 6, l = t & 63;
    int lg = l >> 4, lr = l & 15;
    int rowBase = blockIdx.x * 128;

    const float4* xg = (const float4*)x;     // 32 float4 per row
    const uint4* Wg = (const uint4*)W1b;     // 16 uint4 per row

    // ---- stage A tile, converting f32 -> bf16 ----
#pragma unroll
    for (int it = 0; it < 8; ++it) {
        int idx = it * 256 + t;              // 0..2047
        int r = idx >> 4, s = idx & 15;
        int gr = rowBase + r;
        uint4 v = make_uint4(0, 0, 0, 0);
        if (gr < N) {
            float4 a = xg[(size_t)gr * 32 + 2 * s];
            float4 b = xg[(size_t)gr * 32 + 2 * s + 1];
            v.x = (uint)f2bf(a.x) | ((uint)f2bf(a.y) << 16);
            v.y = (uint)f2bf(a.z) | ((uint)f2bf(a.w) << 16);
            v.z = (uint)f2bf(b.x) | ((uint)f2bf(b.y) << 16);
            v.w = (uint)f2bf(b.z) | ((uint)f2bf(b.w) << 16);
        }
        A4[r * 16 + (s ^ (r & 7))] = v;
    }
    // ---- stage W hop 0 ----
#pragma unroll
    for (int it = 0; it < 8; ++it) {
        int idx = it * 256 + t;
        int r = idx >> 4, s = idx & 15;
        W4s[r * 16 + (s ^ (r & 7))] = Wg[r * 16 + s];
    }
    __syncthreads();

    // deg for this thread's 8 output rows (constant across hops)
    float dreg[2][4];
#pragma unroll
    for (int rt = 0; rt < 2; ++rt)
#pragma unroll
        for (int jj = 0; jj < 4; ++jj) {
            int gr = rowBase + wv * 32 + rt * 16 + lg * 4 + jj;
            dreg[rt][jj] = (gr < N) ? (float)deg[gr] : 0.f;
        }

    for (int j = 0; j < HOP; ++j) {
        f32x4 acc[2][8];
#pragma unroll
        for (int rt = 0; rt < 2; ++rt)
#pragma unroll
            for (int ct = 0; ct < 8; ++ct) acc[rt][ct] = (f32x4){0.f, 0.f, 0.f, 0.f};

#pragma unroll
        for (int ks = 0; ks < 4; ++ks) {
            int slot = ks * 4 + lg;
            bf16x8 af[2], bfr[8];
#pragma unroll
            for (int rt = 0; rt < 2; ++rt) {
                int r = wv * 32 + rt * 16 + lr;
                af[rt] = *(const bf16x8*)&A4[r * 16 + (slot ^ (r & 7))];
            }
#pragma unroll
            for (int ct = 0; ct < 8; ++ct) {
                int r = ct * 16 + lr;
                bfr[ct] = *(const bf16x8*)&W4s[r * 16 + (slot ^ (r & 7))];
            }
#pragma unroll
            for (int rt = 0; rt < 2; ++rt)
#pragma unroll
                for (int ct = 0; ct < 8; ++ct)
                    acc[rt][ct] = __builtin_amdgcn_mfma_f32_16x16x32_bf16(
                        af[rt], bfr[ct], acc[rt][ct], 0, 0, 0);
        }

        // restage W for next hop (all waves done with current W after barrier)
        if (j + 1 < HOP) {
            __syncthreads();
#pragma unroll
            for (int it = 0; it < 8; ++it) {
                int idx = it * 256 + t;
                int r = idx >> 4, s = idx & 15;
                W4s[r * 16 + (s ^ (r & 7))] = Wg[((j + 1) * 128 + r) * 16 + s];
            }
        }

        // epilogue for hop j
        float cv[8];
#pragma unroll
        for (int ct = 0; ct < 8; ++ct) cv[ct] = cvec[j * H + ct * 16 + lr];
#pragma unroll
        for (int rt = 0; rt < 2; ++rt) {
#pragma unroll
            for (int jj = 0; jj < 4; ++jj) {
                int gr = rowBase + wv * 32 + rt * 16 + lg * 4 + jj;
                if (gr < N) {
                    float d = dreg[rt][jj];
#pragma unroll
                    for (int ct = 0; ct < 8; ++ct) {
                        int gc = ct * 16 + lr;
                        float v = acc[rt][ct][jj] + d * cv[ct];
                        if (j == 0) {
                            v = fmaxf(v, 0.f);
                            if (HOP == 1) outf[(size_t)gr * H + gc] = v;
                            else h[(size_t)gr * H + gc] = f2bf(v);
                        } else {
                            bias[(size_t)(j - 1) * N * H + (size_t)gr * H + gc] = f2bf(v);
                        }
                    }
                }
            }
        }
        if (j + 1 < HOP) __syncthreads();
    }
}

// =======================================================================
// Staged-LDS MFMA GEMM (p = h @ W2_i^T)
// =======================================================================

template<int ADD_DEGC, int RELU, int OUT_BF16>
__global__ __launch_bounds__(256)
void gemm_mfma(const ushort* __restrict__ A, const ushort* __restrict__ W,
               const int* __restrict__ deg, const float* __restrict__ cvec,
               void* __restrict__ Cout, int N)
{
    __shared__ uint4 A4[128 * 8];
    __shared__ uint4 W4[128 * 8];
    int t = threadIdx.x;
    int w = t >> 6, l = t & 63;
    int lg = l >> 4, lr = l & 15;
    int rowBase = blockIdx.x * 128;

    f32x4 acc[2][8];
#pragma unroll
    for (int rt = 0; rt < 2; ++rt)
#pragma unroll
        for (int ct = 0; ct < 8; ++ct) acc[rt][ct] = (f32x4){0.f, 0.f, 0.f, 0.f};

    const uint4* Ag = (const uint4*)A;
    const uint4* Wg = (const uint4*)W;

    for (int kc = 0; kc < 2; ++kc) {
        if (kc) __syncthreads();
#pragma unroll
        for (int it = 0; it < 4; ++it) {
            int idx = it * 256 + t;
            int r = idx >> 3, s = idx & 7;
            int gr = rowBase + r;
            uint4 v = make_uint4(0, 0, 0, 0);
            if (gr < N) v = Ag[(size_t)gr * 16 + kc * 8 + s];
            A4[r * 8 + (s ^ (r & 7))] = v;
            W4[r * 8 + (s ^ (r & 7))] = Wg[r * 16 + kc * 8 + s];
        }
        __syncthreads();
#pragma unroll
        for (int kk = 0; kk < 2; ++kk) {
            int slot = kk * 4 + lg;
            bf16x8 af[2], bfr[8];
#pragma unroll
            for (int rt = 0; rt < 2; ++rt) {
                int r = w * 32 + rt * 16 + lr;
                af[rt] = *(const bf16x8*)&A4[r * 8 + (slot ^ (r & 7))];
            }
#pragma unroll
            for (int ct = 0; ct < 8; ++ct) {
                int r = ct * 16 + lr;
                bfr[ct] = *(const bf16x8*)&W4[r * 8 + (slot ^ (r & 7))];
            }
#pragma unroll
            for (int rt = 0; rt < 2; ++rt)
#pragma unroll
                for (int ct = 0; ct < 8; ++ct)
                    acc[rt][ct] = __builtin_amdgcn_mfma_f32_16x16x32_bf16(
                        af[rt], bfr[ct], acc[rt][ct], 0, 0, 0);
        }
    }

    float cv[8];
    if (ADD_DEGC) {
#pragma unroll
        for (int ct = 0; ct < 8; ++ct) cv[ct] = cvec[ct * 16 + lr];
    }
#pragma unroll
    for (int rt = 0; rt < 2; ++rt) {
#pragma unroll
        for (int j = 0; j < 4; ++j) {
            int gr = rowBase + w * 32 + rt * 16 + lg * 4 + j;
            if (gr < N) {
                float d = ADD_DEGC ? (float)deg[gr] : 0.f;
#pragma unroll
                for (int ct = 0; ct < 8; ++ct) {
                    int gc = ct * 16 + lr;
                    float v = acc[rt][ct][j];
                    if (ADD_DEGC) v += d * cv[ct];
                    if (RELU) v = fmaxf(v, 0.f);
                    if (OUT_BF16) ((ushort*)Cout)[(size_t)gr * H + gc] = f2bf(v);
                    else ((float*)Cout)[(size_t)gr * H + gc] = v;
                }
            }
        }
    }
}

// =======================================================================
// aggregation: dst[n] = relu(biasb[n] + sum_{e in row n} p[cols[e]])
// one wave per node; 8-deep gather unroll
// =======================================================================

template<int OUT_BF16>
__global__ void aggregate_relu3(const ushort* __restrict__ biasb, const ushort* __restrict__ p,
                                const int* __restrict__ off, const int* __restrict__ cols,
                                void* __restrict__ dst, int N)
{
    int node = blockIdx.x * 4 + (threadIdx.x >> 6);
    if (node >= N) return;
    int l = threadIdx.x & 63;
    int s = off[node], e = off[node + 1];
    const uint* pu = (const uint*)p;     // [N][64]
    float ax = 0.f, ay = 0.f;
    int i = s;
    for (; i + 8 <= e; i += 8) {
        uint v0 = pu[(size_t)cols[i]     * 64 + l];
        uint v1 = pu[(size_t)cols[i + 1] * 64 + l];
        uint v2 = pu[(size_t)cols[i + 2] * 64 + l];
        uint v3 = pu[(size_t)cols[i + 3] * 64 + l];
        uint v4 = pu[(size_t)cols[i + 4] * 64 + l];
        uint v5 = pu[(size_t)cols[i + 5] * 64 + l];
        uint v6 = pu[(size_t)cols[i + 6] * 64 + l];
        uint v7 = pu[(size_t)cols[i + 7] * 64 + l];
        ax += bf_lo(v0) + bf_lo(v1) + bf_lo(v2) + bf_lo(v3)
            + bf_lo(v4) + bf_lo(v5) + bf_lo(v6) + bf_lo(v7);
        ay += bf_hi(v0) + bf_hi(v1) + bf_hi(v2) + bf_hi(v3)
            + bf_hi(v4) + bf_hi(v5) + bf_hi(v6) + bf_hi(v7);
    }
    for (; i + 4 <= e; i += 4) {
        uint v0 = pu[(size_t)cols[i]     * 64 + l];
        uint v1 = pu[(size_t)cols[i + 1] * 64 + l];
        uint v2 = pu[(size_t)cols[i + 2] * 64 + l];
        uint v3 = pu[(size_t)cols[i + 3] * 64 + l];
        ax += bf_lo(v0) + bf_lo(v1) + bf_lo(v2) + bf_lo(v3);
        ay += bf_hi(v0) + bf_hi(v1) + bf_hi(v2) + bf_hi(v3);
    }
    for (; i < e; ++i) {
        uint v = pu[(size_t)cols[i] * 64 + l];
        ax += bf_lo(v);
        ay += bf_hi(v);
    }
    uint bb = ((const uint*)biasb)[(size_t)node * 64 + l];
    float ox = fmaxf(bf_lo(bb) + ax, 0.f);
    float oy = fmaxf(bf_hi(bb) + ay, 0.f);
    if (OUT_BF16) {
        ((uint*)dst)[(size_t)node * 64 + l] = (uint)f2bf(ox) | ((uint)f2bf(oy) << 16);
    } else {
        ((float2*)dst)[(size_t)node * 64 + l] = make_float2(ox, oy);
    }
}

// =======================================================================
// launch
// =======================================================================

extern "C" void kernel_launch(void* const* d_in, const int* in_sizes, int n_in,
                              void* d_out, int out_size, void* d_ws, size_t ws_size,
                              hipStream_t stream)
{
    const float* x  = (const float*)d_in[0];
    const int*   ei = (const int*)d_in[1];
    const float* W1 = (const float*)d_in[2];
    const float* W2 = (const float*)d_in[3];
    const float* W3 = (const float*)d_in[4];
    const float* W4 = (const float*)d_in[5];
    int N   = in_sizes[0] / H;
    int E   = in_sizes[1] / 2;
    int HOP = in_sizes[2] / (H * H);

    int NB   = (N + 1023) >> 10;
    int NBLK = (E + 4095) >> 12;
    int M    = NB * NBLK;

    char* ws = (char*)d_ws;
    int*   deg   = (int*)ws;                  // N
    int*   off   = deg + N;                   // N+1
    int*   colss = off + N + 1;               // E
    int*   cntg  = colss + E;                 // M
    int*   ebase = cntg + M;                  // M+1
    int*   bsum  = ebase + M + 1;             // <=1024
    float* cvec  = (float*)(bsum + 1024);     // HOP*H
    size_t fo = (((size_t)((char*)(cvec + HOP * H) - ws)) + 255) & ~(size_t)255;
    int2*  ebuf  = (int2*)(ws + fo);          // E int2
    ushort* W1b  = (ushort*)(ebuf + E);       // HOP*H*H
    ushort* W2b  = W1b + (size_t)HOP * H * H; // HOP*H*H
    ushort* p    = W2b + (size_t)HOP * H * H; // N*H
    ushort* h    = p + (size_t)N * H;         // N*H
    ushort* bias = h + (size_t)N * H;         // (HOP-1)*N*H

    // ---- CSR build ----
    bucket_hist<<<NBLK, 256, 0, stream>>>(ei, E, NB, NBLK, cntg);
    int Bq = (M + 511) / 512;
    scan_reduce<<<Bq, 256, 0, stream>>>(cntg, bsum, M);
    scan_bsums<<<1, 1024, 0, stream>>>(bsum, ebase, Bq, M);
    scan_write<<<Bq, 256, 0, stream>>>(cntg, bsum, ebase, M);
    bucket_scatter<<<NBLK, 256, 0, stream>>>(ei, E, NB, NBLK, ebase, ebuf);
    bucket_csr<<<NB, 1024, 0, stream>>>(ebuf, ebase, NB, NBLK, E, N, deg, off, colss);

    cvec_kernel<<<HOP, H, 0, stream>>>(W3, W4, cvec);

    // ---- weight casts (tiny) ----
    int nw8 = HOP * H * H / 8;
    cast_bf16<<<(nw8 + 255) / 256, 256, 0, stream>>>(W1, W1b, nw8);
    cast_bf16<<<(nw8 + 255) / 256, 256, 0, stream>>>(W2, W2b, nw8);

    int gblocks = (N + 127) / 128;
    float* out = (float*)d_out;

    // h = relu(x@W1[0]^T + deg*c0); bias[j-1] = x@W1[j]^T + deg*c_j
    multi_xproj<<<gblocks, 256, 0, stream>>>(x, W1b, deg, cvec, h, bias, out, N, HOP);
    if (HOP == 1) return;

    for (int i = 1; i < HOP; ++i) {
        int last = (i == HOP - 1);
        // p = h @ W2[i]^T (bf16)
        gemm_mfma<0, 0, 1><<<gblocks, 256, 0, stream>>>(h, W2b + (size_t)i * H * H,
                                                        nullptr, nullptr, p, N);
        // dst = relu(bias[i-1] + A p)
        if (last)
            aggregate_relu3<0><<<(N + 3) / 4, 256, 0, stream>>>(bias + (size_t)(i - 1) * N * H,
                                                                p, off, colss, out, N);
        else
            aggregate_relu3<1><<<(N + 3) / 4, 256, 0, stream>>>(bias + (size_t)(i - 1) * N * H,
                                                                p, off, colss, h, N);
    }
}